// Round 5
// baseline (300.930 us; speedup 1.0000x reference)
//
#include <hip/hip_runtime.h>
#include <hip/hip_bf16.h>

#define N_TOK 4096
#define D_IN  512
#define D_HID 256
#define N_OUT 40

typedef _Float16 half8 __attribute__((ext_vector_type(8)));
typedef _Float16 half4 __attribute__((ext_vector_type(4)));
typedef float    f32x4 __attribute__((ext_vector_type(4)));

// async 16B/lane global->LDS DMA; lds dst is wave-uniform base (+lane*16 implicit)
__device__ __forceinline__ void async_copy16(const _Float16* g, _Float16* l) {
  __builtin_amdgcn_global_load_lds(
      (const __attribute__((address_space(1))) unsigned int*)(g),
      (__attribute__((address_space(3))) unsigned int*)(l), 16, 0, 0);
}

// ---------------------------------------------------------------------------
// prep: h -> fp16; W transposes via LDS 64x64 tiles (coalesced both sides)
// ---------------------------------------------------------------------------
__device__ __forceinline__ void transpose_tile(const float* __restrict__ src, int in_ncols,
                                               _Float16* __restrict__ dst, int out_ncols,
                                               int i0, int d0, float* lds /* 64*65 */)
{
  int tid = threadIdx.x;
  int l15 = tid & 15, l4 = tid >> 4;
#pragma unroll
  for (int p = 0; p < 4; p++) {
    int ii = p * 16 + l4;
    float4 x = *(const float4*)(src + (size_t)(i0 + ii) * in_ncols + d0 + l15 * 4);
    lds[(l15 * 4 + 0) * 65 + ii] = x.x;
    lds[(l15 * 4 + 1) * 65 + ii] = x.y;
    lds[(l15 * 4 + 2) * 65 + ii] = x.z;
    lds[(l15 * 4 + 3) * 65 + ii] = x.w;
  }
  __syncthreads();
  int dd = tid >> 2, chunk = tid & 3;
  half8 o0, o1;
#pragma unroll
  for (int j = 0; j < 8; j++) o0[j] = (_Float16)lds[dd * 65 + chunk * 16 + j];
#pragma unroll
  for (int j = 0; j < 8; j++) o1[j] = (_Float16)lds[dd * 65 + chunk * 16 + 8 + j];
  *(half8*)(dst + (size_t)(d0 + dd) * out_ncols + i0 + chunk * 16) = o0;
  *(half8*)(dst + (size_t)(d0 + dd) * out_ncols + i0 + chunk * 16 + 8) = o1;
}

__global__ void prep_kernel(const float* __restrict__ h, const float* __restrict__ Wq,
                            const float* __restrict__ Wk, const float* __restrict__ Wv,
                            const float* __restrict__ Wo, const float* __restrict__ Wp,
                            _Float16* __restrict__ h16, _Float16* __restrict__ Wqt,
                            _Float16* __restrict__ Wkt, _Float16* __restrict__ Wvt,
                            _Float16* __restrict__ Wot, _Float16* __restrict__ Wpt)
{
  __shared__ float lds[64 * 65];
  int b = blockIdx.x, tid = threadIdx.x;
  if (b < 1024) {                              // h -> h16 (4096x512)
    int base = b * 2048 + tid * 8;
    float4 x0 = *(const float4*)(h + base);
    float4 x1 = *(const float4*)(h + base + 4);
    half8 o;
    o[0]=(_Float16)x0.x; o[1]=(_Float16)x0.y; o[2]=(_Float16)x0.z; o[3]=(_Float16)x0.w;
    o[4]=(_Float16)x1.x; o[5]=(_Float16)x1.y; o[6]=(_Float16)x1.z; o[7]=(_Float16)x1.w;
    *(half8*)(h16 + base) = o;
  } else if (b < 1216) {                       // Wq/Wk/Wv transpose, 64x64 tiles
    int t = b - 1024;
    int mat = t >> 5;
    int m = mat >> 1, head = mat & 1;
    const float* W = (m==0 ? Wq : (m==1 ? Wk : Wv)) + head * (D_IN * D_HID);
    _Float16* Wt   = (m==0 ? Wqt : (m==1 ? Wkt : Wvt)) + head * (D_IN * D_HID);
    int tt = t & 31;
    int i0 = (tt >> 2) * 64, d0 = (tt & 3) * 64;
    transpose_tile(W, D_HID, Wt, D_IN, i0, d0, lds);
  } else if (b < 1280) {                       // Wo transpose (512x512)
    int t = b - 1216;
    int i0 = (t >> 3) * 64, d0 = (t & 7) * 64;
    transpose_tile(Wo, D_IN, Wot, D_IN, i0, d0, lds);
  } else {                                     // Wp transpose+pad to [48][512]
    int blk = b - 1280;
    int idx = blk * 1024 + tid * 4;
    int j = idx >> 9, i = idx & 511;
    half4 o;
#pragma unroll
    for (int u = 0; u < 4; u++)
      o[u] = (j < N_OUT) ? (_Float16)Wp[(i + u) * N_OUT + j] : (_Float16)0.f;
    *(half4*)(Wpt + j * D_IN + i) = o;
  }
}

// ---------------------------------------------------------------------------
// proj: unified m97-style 128x128-tile GEMM, BK=64, LDS-staged A and B.
// ---------------------------------------------------------------------------
__global__ __launch_bounds__(256, 2) void proj_kernel(
    const _Float16* __restrict__ h16, const _Float16* __restrict__ W6 /*Wqt base*/,
    const _Float16* __restrict__ Wvt,
    const float* __restrict__ bq, const float* __restrict__ bk,
    const float* __restrict__ bv,
    _Float16* __restrict__ Q16, _Float16* __restrict__ K16,
    _Float16* __restrict__ VT16)
{
  __shared__ __align__(16) _Float16 Atile[128 * 64];
  __shared__ __align__(16) _Float16 Btile[128 * 64];

  int b = blockIdx.x;
  int tid = threadIdx.x, w = tid >> 6, lane = tid & 63, quad = lane >> 4, cL = lane & 15;
  int wr = w >> 1, wc = w & 1;

  const _Float16 *Asrc, *Bsrc;
  int isV;
  int m0 = 0, n0 = 0, head = 0, mh = 0;
  if (b < 256) {
    isV = 0;
    m0 = (b >> 3) * 128;
    int ct = b & 7;
    mh = ct >> 1;
    n0 = (ct & 1) * 128;
    Asrc = h16 + (size_t)m0 * D_IN;
    Bsrc = W6 + (size_t)(ct * 128) * D_IN;
  } else {
    isV = 1;
    int t = b - 256;
    head = t >> 6;
    int tt = t & 63;
    m0 = (tt >> 5) * 128;
    n0 = (tt & 31) * 128;
    Asrc = Wvt + (size_t)head * (D_HID * D_IN) + (size_t)m0 * D_IN;
    Bsrc = h16 + (size_t)n0 * D_IN;
  }

  const f32x4 z4 = {0.f, 0.f, 0.f, 0.f};
  f32x4 acc[4][4];
#pragma unroll
  for (int i = 0; i < 4; i++)
#pragma unroll
    for (int j = 0; j < 4; j++) acc[i][j] = z4;

  int r8 = lane >> 3, chs = (lane & 7) ^ r8;

  for (int kc = 0; kc < 8; kc++) {
    __syncthreads();
#pragma unroll
    for (int g = 0; g < 4; g++) {
      int row = (w * 4 + g) * 8 + r8;
      async_copy16(Asrc + (size_t)row * D_IN + kc * 64 + chs * 8, Atile + (w * 4 + g) * 512);
      async_copy16(Bsrc + (size_t)row * D_IN + kc * 64 + chs * 8, Btile + (w * 4 + g) * 512);
    }
    __syncthreads();
#pragma unroll
    for (int kk = 0; kk < 2; kk++) {
      int ch = ((kk * 4 + quad) ^ (cL & 7)) * 8;
      half8 a[4], bf[4];
#pragma unroll
      for (int mt = 0; mt < 4; mt++)
        a[mt] = *(const half8*)(Atile + (wr * 64 + mt * 16 + cL) * 64 + ch);
#pragma unroll
      for (int nt = 0; nt < 4; nt++)
        bf[nt] = *(const half8*)(Btile + (wc * 64 + nt * 16 + cL) * 64 + ch);
#pragma unroll
      for (int mt = 0; mt < 4; mt++)
#pragma unroll
        for (int nt = 0; nt < 4; nt++)
          acc[mt][nt] = __builtin_amdgcn_mfma_f32_16x16x32_f16(a[mt], bf[nt], acc[mt][nt], 0, 0, 0);
    }
  }

  if (!isV) {
    _Float16* Out = (mh < 2 ? Q16 + (size_t)mh * (N_TOK * D_HID)
                            : K16 + (size_t)(mh - 2) * (N_TOK * D_HID));
    const float* bias = (mh < 2 ? bq + mh * D_HID : bk + (mh - 2) * D_HID);
#pragma unroll
    for (int mt = 0; mt < 4; mt++) {
      int row = m0 + wr * 64 + mt * 16 + quad * 4;
#pragma unroll
      for (int nt = 0; nt < 4; nt++) {
        int colg = n0 + wc * 64 + nt * 16 + cL;
        float bb = bias[colg];
#pragma unroll
        for (int reg = 0; reg < 4; reg++)
          Out[(size_t)(row + reg) * D_HID + colg] = (_Float16)(acc[mt][nt][reg] + bb);
      }
    }
  } else {
    _Float16* VTh = VT16 + (size_t)head * (N_TOK * D_HID);
    const float* bvh = bv + head * D_HID;
#pragma unroll
    for (int mt = 0; mt < 4; mt++) {
      int d0r = m0 + wr * 64 + mt * 16 + quad * 4;
      float bvv[4];
#pragma unroll
      for (int reg = 0; reg < 4; reg++) bvv[reg] = bvh[d0r + reg];
#pragma unroll
      for (int nt = 0; nt < 4; nt++) {
        int tok = n0 + wc * 64 + nt * 16 + cL;
#pragma unroll
        for (int reg = 0; reg < 4; reg++)
          VTh[(size_t)(d0r + reg) * N_TOK + tok] = (_Float16)(acc[mt][nt][reg] + bvv[reg]);
      }
    }
  }
}

// ---------------------------------------------------------------------------
// attn v5: 32 Q-rows/wave (2 m-tiles), double-buffered K/V LDS staging
// (1 barrier/iter, DMA drains during compute), fixed-shift softmax
// p = clamp(exp(s-22)) (no max/sum reductions, no rescale; row-sum l via an
// extra MFMA with a ones B-fragment). Per-slice normalized O (fp16) + l (f32);
// merge does the l-weighted average. grid 256 = 2 heads x 4 gs x 32 rowgroups
// of 128 rows; 1 WG/CU, 4 waves, LDS 146.5 KB.
// ---------------------------------------------------------------------------
__global__ __launch_bounds__(256, 1) void attn_kernel(
    const float* __restrict__ adj, const _Float16* __restrict__ Q16,
    const _Float16* __restrict__ K16, const _Float16* __restrict__ VT16,
    _Float16* __restrict__ Opart, float* __restrict__ Lpart)
{
  __shared__ __align__(16) _Float16 Kbuf[2][64 * 256];   // 2 x 32 KB
  __shared__ __align__(16) _Float16 Vbuf[2][256 * 64];   // 2 x 32 KB
  __shared__ __align__(16) _Float16 Pbuf[4][32 * 72];    // 18 KB
  __shared__ float Lsh[4][32];

  int b = blockIdx.x;
  int sl = b & 7;                              // slice = head*4+gs -> XCD-pinned
  int head = sl >> 2, gs = sl & 3;
  int tid = threadIdx.x;
  int w = tid >> 6, lane = tid & 63, quad = lane >> 4, cL = lane & 15;
  int l5 = lane >> 5, l31 = lane & 31, l3h = lane >> 3, l7 = lane & 7;

  const _Float16* Qh = Q16 + head * (N_TOK * D_HID);
  const _Float16* Kh = K16 + head * (N_TOK * D_HID);
  const _Float16* Vh = VT16 + head * (N_TOK * D_HID);
  const float* adjh = adj + (size_t)head * N_TOK * N_TOK;

  int qrow0 = (b >> 3) * 128 + w * 32;
  int nstart = gs * 1024;
  const f32x4 z4 = {0.f, 0.f, 0.f, 0.f};

  // Q fragments: 2 m-tiles x 8 k-steps (verified 16x16x32 A layout)
  half8 qf[2][8];
#pragma unroll
  for (int mt = 0; mt < 2; mt++)
#pragma unroll
    for (int ks = 0; ks < 8; ks++)
      qf[mt][ks] = *(const half8*)(Qh + (qrow0 + mt * 16 + cL) * D_HID + ks * 32 + quad * 8);

  const float* adjP[2][4];
#pragma unroll
  for (int mt = 0; mt < 2; mt++)
#pragma unroll
    for (int reg = 0; reg < 4; reg++)
      adjP[mt][reg] = adjh + (size_t)(qrow0 + mt * 16 + quad * 4 + reg) * N_TOK + nstart + cL;

  f32x4 acc[2][16];
  f32x4 accl[2];
#pragma unroll
  for (int mt = 0; mt < 2; mt++) {
    accl[mt] = z4;
#pragma unroll
    for (int dt = 0; dt < 16; dt++) acc[mt][dt] = z4;
  }

  _Float16* pb = Pbuf[w];

  half8 onesf;
#pragma unroll
  for (int j = 0; j < 8; j++) onesf[j] = (cL == 0) ? (_Float16)1.0f : (_Float16)0.0f;

  // prologue: stage iteration 0 into buf 0
#pragma unroll
  for (int i = 0; i < 8; i++) {
    int g = w * 8 + i;
    int rK = 2 * g + l5;
    int cK = l31 ^ (rK & 7);
    async_copy16(Kh + (size_t)(nstart + rK) * D_HID + cK * 8, Kbuf[0] + g * 512);
    int rV = 8 * g + l3h;
    int cV = l7 ^ (rV & 7);
    async_copy16(Vh + (size_t)rV * N_TOK + nstart + cV * 8, Vbuf[0] + g * 512);
  }

  for (int it = 0; it < 16; ++it) {
    int cur = it & 1;
    __syncthreads();   // drains stage(it) DMA; all waves done reading buf[1-cur]

    // adj loads FIRST (so their vmcnt wait doesn't force the DMA below to drain)
    float av[2][4][4];
#pragma unroll
    for (int mt = 0; mt < 2; mt++)
#pragma unroll
      for (int reg = 0; reg < 4; reg++)
#pragma unroll
        for (int ct = 0; ct < 4; ct++)
          av[mt][ct][reg] = __builtin_nontemporal_load(adjP[mt][reg] + it * 64 + ct * 16);

    // stage it+1 into the other buffer (drained by NEXT iteration's barrier)
    if (it < 15) {
      int n1 = nstart + (it + 1) * 64;
      _Float16* Kd = Kbuf[1 - cur];
      _Float16* Vd = Vbuf[1 - cur];
#pragma unroll
      for (int i = 0; i < 8; i++) {
        int g = w * 8 + i;
        int rK = 2 * g + l5;
        int cK = l31 ^ (rK & 7);
        async_copy16(Kh + (size_t)(n1 + rK) * D_HID + cK * 8, Kd + g * 512);
        int rV = 8 * g + l3h;
        int cV = l7 ^ (rV & 7);
        async_copy16(Vh + (size_t)rV * N_TOK + n1 + cV * 8, Vd + g * 512);
      }
    }

    // ---- QK^T from LDS (B-frags shared across the 2 m-tiles) ----
    const _Float16* Kb = Kbuf[cur];
    f32x4 s[2][4];
#pragma unroll
    for (int mt = 0; mt < 2; mt++)
#pragma unroll
      for (int ct = 0; ct < 4; ct++) s[mt][ct] = z4;
#pragma unroll
    for (int ks = 0; ks < 8; ks++) {
#pragma unroll
      for (int ct = 0; ct < 4; ct++) {
        int rK = ct * 16 + cL;
        int ck = (ks * 4 + quad) ^ (rK & 7);
        half8 kf = *(const half8*)(Kb + rK * 256 + ck * 8);
        s[0][ct] = __builtin_amdgcn_mfma_f32_16x16x32_f16(qf[0][ks], kf, s[0][ct], 0, 0, 0);
        s[1][ct] = __builtin_amdgcn_mfma_f32_16x16x32_f16(qf[1][ks], kf, s[1][ct], 0, 0, 0);
      }
    }

    // ---- fixed-shift exp, no reductions: p = min(exp(s*adj - 22), 60000) ----
#pragma unroll
    for (int mt = 0; mt < 2; mt++)
#pragma unroll
      for (int ct = 0; ct < 4; ct++)
#pragma unroll
        for (int reg = 0; reg < 4; reg++) {
          float sc = s[mt][ct][reg] * av[mt][ct][reg];
          float p = __builtin_amdgcn_exp2f(sc * 1.44269504f - 31.7392909f);
          p = fminf(p, 60000.0f);
          pb[(mt * 16 + quad * 4 + reg) * 72 + ct * 16 + cL] = (_Float16)p;
        }

    // ---- PV from LDS (+ row-sum l via ones B-frag) ----
    const _Float16* Vb = Vbuf[cur];
#pragma unroll
    for (int k2 = 0; k2 < 2; k2++) {
      half8 pa0 = *(const half8*)(pb + cL * 72 + k2 * 32 + quad * 8);
      half8 pa1 = *(const half8*)(pb + (16 + cL) * 72 + k2 * 32 + quad * 8);
      accl[0] = __builtin_amdgcn_mfma_f32_16x16x32_f16(pa0, onesf, accl[0], 0, 0, 0);
      accl[1] = __builtin_amdgcn_mfma_f32_16x16x32_f16(pa1, onesf, accl[1], 0, 0, 0);
#pragma unroll
      for (int dt = 0; dt < 16; dt++) {
        int rV = dt * 16 + cL;
        int cv = (k2 * 4 + quad) ^ (rV & 7);
        half8 vf = *(const half8*)(Vb + rV * 64 + cv * 8);
        acc[0][dt] = __builtin_amdgcn_mfma_f32_16x16x32_f16(pa0, vf, acc[0][dt], 0, 0, 0);
        acc[1][dt] = __builtin_amdgcn_mfma_f32_16x16x32_f16(pa1, vf, acc[1][dt], 0, 0, 0);
      }
    }
  }

  // ---- epilogue: broadcast l within wave via LDS, store normalized O + l ----
  if (cL == 0) {
#pragma unroll
    for (int mt = 0; mt < 2; mt++)
#pragma unroll
      for (int reg = 0; reg < 4; reg++)
        Lsh[w][mt * 16 + quad * 4 + reg] = accl[mt][reg];
  }
#pragma unroll
  for (int mt = 0; mt < 2; mt++)
#pragma unroll
    for (int reg = 0; reg < 4; reg++) {
      float lr = Lsh[w][mt * 16 + quad * 4 + reg];
      float inv = 1.0f / fmaxf(lr, 1e-30f);
      int grow = sl * N_TOK + qrow0 + mt * 16 + quad * 4 + reg;
#pragma unroll
      for (int dt = 0; dt < 16; dt++)
        Opart[(size_t)grow * D_HID + dt * 16 + cL] = (_Float16)(acc[mt][dt][reg] * inv);
      if (cL == 0) Lpart[grow] = lr;
    }
}

// ---------------------------------------------------------------------------
// merge: l-weighted average of the 4 per-slice normalized O -> Xf [4096][512]
// ---------------------------------------------------------------------------
__global__ void merge_kernel(const _Float16* __restrict__ Opart,
                             const float* __restrict__ Lpart,
                             _Float16* __restrict__ Xf)
{
  int t = blockIdx.x * 256 + threadIdx.x;
  int dg = (t & 63) << 2;
  int n = (t >> 6) & (N_TOK - 1);
  int head = t >> 18;
  float osum[4] = {0.f, 0.f, 0.f, 0.f};
  float lsum = 0.f;
#pragma unroll
  for (int s = 0; s < 4; s++) {
    int idx = (head * 4 + s) * N_TOK + n;
    float lw = Lpart[idx];
    half4 os = *(const half4*)(Opart + (size_t)idx * D_HID + dg);
    lsum += lw;
#pragma unroll
    for (int u = 0; u < 4; u++) osum[u] += lw * (float)os[u];
  }
  float rl = 1.0f / fmaxf(lsum, 1e-30f);
  half4 res;
#pragma unroll
  for (int u = 0; u < 4; u++) res[u] = (_Float16)(osum[u] * rl);
  *(half4*)(Xf + (size_t)n * D_IN + head * D_HID + dg) = res;
}

// ---------------------------------------------------------------------------
// final: z = Xf@Wo + bo -> LayerNorm -> softmax(M@Wp + bp) -> out [4096][40]
// ---------------------------------------------------------------------------
__global__ __launch_bounds__(256, 1) void final_kernel(
    const _Float16* __restrict__ Xf, const _Float16* __restrict__ Wot,
    const _Float16* __restrict__ Wpt, const float* __restrict__ bo,
    const float* __restrict__ gamma, const float* __restrict__ beta,
    const float* __restrict__ bp, float* __restrict__ out)
{
  __shared__ __align__(16) _Float16 Btile[512 * 64];
  __shared__ __align__(16) _Float16 Mlds[16 * 520];
  __shared__ float outs[16 * 48];
  __shared__ float lnsum[4][16], lnsq[4][16];
  __shared__ float smx[16], srl[16];

  int rowbase = blockIdx.x * 16;
  int tid = threadIdx.x, w = tid >> 6, lane = tid & 63, quad = lane >> 4, cL = lane & 15;
  const f32x4 z4 = {0.f, 0.f, 0.f, 0.f};

  half8 af[16];
#pragma unroll
  for (int t = 0; t < 16; t++)
    af[t] = *(const half8*)(Xf + (rowbase + cL) * D_IN + t * 32 + quad * 8);

  f32x4 acc[8];
#pragma unroll
  for (int i = 0; i < 8; i++) acc[i] = z4;

  int r8 = lane >> 3, chs = (lane & 7) ^ r8;

  for (int kc = 0; kc < 8; kc++) {
    __syncthreads();
#pragma unroll
    for (int g = 0; g < 16; g++) {
      int row = (w * 16 + g) * 8 + r8;
      async_copy16(Wot + (size_t)row * D_IN + kc * 64 + chs * 8, Btile + (w * 16 + g) * 512);
    }
    __syncthreads();
#pragma unroll
    for (int kk = 0; kk < 2; kk++) {
      int ch = ((kk * 4 + quad) ^ (cL & 7)) * 8;
      half8 a = af[kc * 2 + kk];
      half8 bf[8];
#pragma unroll
      for (int nt = 0; nt < 8; nt++)
        bf[nt] = *(const half8*)(Btile + (w * 128 + nt * 16 + cL) * 64 + ch);
#pragma unroll
      for (int nt = 0; nt < 8; nt++)
        acc[nt] = __builtin_amdgcn_mfma_f32_16x16x32_f16(a, bf[nt], acc[nt], 0, 0, 0);
    }
  }

  float sum[4] = {0, 0, 0, 0}, sq[4] = {0, 0, 0, 0};
#pragma unroll
  for (int nt = 0; nt < 8; nt++) {
    int col = w * 128 + nt * 16 + cL;
    float bb = bo[col];
#pragma unroll
    for (int reg = 0; reg < 4; reg++) {
      float z = acc[nt][reg] + bb;
      acc[nt][reg] = z;
      sum[reg] += z;
      sq[reg] += z * z;
    }
  }
#pragma unroll
  for (int reg = 0; reg < 4; reg++) {
#pragma unroll
    for (int msk = 1; msk < 16; msk <<= 1) {
      sum[reg] += __shfl_xor(sum[reg], msk, 16);
      sq[reg]  += __shfl_xor(sq[reg], msk, 16);
    }
  }
  if (cL == 0) {
#pragma unroll
    for (int reg = 0; reg < 4; reg++) {
      lnsum[w][quad * 4 + reg] = sum[reg];
      lnsq[w][quad * 4 + reg]  = sq[reg];
    }
  }
  __syncthreads();
  float mean[4], rstd[4];
#pragma unroll
  for (int reg = 0; reg < 4; reg++) {
    int row = quad * 4 + reg;
    float s  = lnsum[0][row] + lnsum[1][row] + lnsum[2][row] + lnsum[3][row];
    float s2 = lnsq[0][row]  + lnsq[1][row]  + lnsq[2][row]  + lnsq[3][row];
    float mu = s * (1.0f / 512.0f);
    float var = s2 * (1.0f / 512.0f) - mu * mu;
    mean[reg] = mu;
    rstd[reg] = rsqrtf(var + 1e-5f);
  }
#pragma unroll
  for (int nt = 0; nt < 8; nt++) {
    int col = w * 128 + nt * 16 + cL;
    float g = gamma[col], be = beta[col];
#pragma unroll
    for (int reg = 0; reg < 4; reg++) {
      float mval = (acc[nt][reg] - mean[reg]) * rstd[reg] * g + be;
      Mlds[(quad * 4 + reg) * 520 + col] = (_Float16)mval;
    }
  }
  __syncthreads();
  if (w < 3) {
    int jt = w;
    f32x4 a2 = z4;
#pragma unroll
    for (int t = 0; t < 16; t++) {
      half8 am = *(const half8*)(Mlds + cL * 520 + t * 32 + quad * 8);
      half8 bm = *(const half8*)(Wpt + (jt * 16 + cL) * D_IN + t * 32 + quad * 8);
      a2 = __builtin_amdgcn_mfma_f32_16x16x32_f16(am, bm, a2, 0, 0, 0);
    }
    int col = jt * 16 + cL;
    float bpv = (col < N_OUT) ? bp[col] : 0.0f;
#pragma unroll
    for (int reg = 0; reg < 4; reg++)
      outs[(quad * 4 + reg) * 48 + col] = a2[reg] + bpv;
  }
  __syncthreads();
  if (tid < 16) {
    int row = tid;
    float mx = -1e30f;
    for (int j = 0; j < N_OUT; j++) mx = fmaxf(mx, outs[row * 48 + j]);
    float ssum = 0.f;
    for (int j = 0; j < N_OUT; j++) ssum += __expf(outs[row * 48 + j] - mx);
    smx[row] = mx;
    srl[row] = 1.0f / ssum;
  }
  __syncthreads();
#pragma unroll
  for (int i = 0; i < 3; i++) {
    int lin = tid + 256 * i;
    if (lin < 16 * N_OUT) {
      int row = lin / N_OUT, col = lin % N_OUT;
      out[(size_t)(rowbase + row) * N_OUT + col] =
          __expf(outs[row * 48 + col] - smx[row]) * srl[row];
    }
  }
}

// ---------------------------------------------------------------------------
// Workspace layout (bytes, 256-aligned). Opart overlays buffers dead by attn
// time (h16, Wqt/Wkt/Wvt). Total 34.39 MB.
// ---------------------------------------------------------------------------
#define OFF_WOT   0u
#define OFF_WPT   524288u
#define OFF_Q16   573440u
#define OFF_K16   4767744u
#define OFF_VT16  8962048u
#define OFF_LP    13287424u
#define OFF_XF    13418496u
#define OFF_OP    17612800u
// overlay (dead before attn):
#define OFF_H16   17612800u
#define OFF_WQT   21807104u
#define OFF_WKT   22331392u
#define OFF_WVT   22855680u

extern "C" void kernel_launch(void* const* d_in, const int* in_sizes, int n_in,
                              void* d_out, int out_size, void* d_ws, size_t ws_size,
                              hipStream_t stream)
{
  const float* adj   = (const float*)d_in[0];
  const float* h     = (const float*)d_in[1];
  const float* Wq    = (const float*)d_in[2];
  const float* bq    = (const float*)d_in[3];
  const float* Wk    = (const float*)d_in[4];
  const float* bk    = (const float*)d_in[5];
  const float* Wv    = (const float*)d_in[6];
  const float* bv    = (const float*)d_in[7];
  const float* Wo    = (const float*)d_in[8];
  const float* bo    = (const float*)d_in[9];
  const float* gamma = (const float*)d_in[10];
  const float* beta  = (const float*)d_in[11];
  const float* Wp    = (const float*)d_in[12];
  const float* bp    = (const float*)d_in[13];
  float* out = (float*)d_out;
  char* ws = (char*)d_ws;

  _Float16* h16   = (_Float16*)(ws + OFF_H16);
  _Float16* Wqt   = (_Float16*)(ws + OFF_WQT);
  _Float16* Wkt   = (_Float16*)(ws + OFF_WKT);
  _Float16* Wvt   = (_Float16*)(ws + OFF_WVT);
  _Float16* Wot   = (_Float16*)(ws + OFF_WOT);
  _Float16* Wpt   = (_Float16*)(ws + OFF_WPT);
  _Float16* Q16   = (_Float16*)(ws + OFF_Q16);
  _Float16* K16   = (_Float16*)(ws + OFF_K16);
  _Float16* VT16  = (_Float16*)(ws + OFF_VT16);
  _Float16* Opart = (_Float16*)(ws + OFF_OP);
  float*    Lpart = (float*)(ws + OFF_LP);
  _Float16* Xf    = (_Float16*)(ws + OFF_XF);

  prep_kernel<<<1304, 256, 0, stream>>>(h, Wq, Wk, Wv, Wo, Wp,
                                        h16, Wqt, Wkt, Wvt, Wot, Wpt);
  proj_kernel<<<384, 256, 0, stream>>>(h16, Wqt, Wvt, bq, bk, bv,
                                       Q16, K16, VT16);
  attn_kernel<<<256, 256, 0, stream>>>(adj, Q16, K16, VT16, Opart, Lpart);
  merge_kernel<<<2048, 256, 0, stream>>>(Opart, Lpart, Xf);
  final_kernel<<<256, 256, 0, stream>>>(Xf, Wot, Wpt, bo, gamma, beta, bp, out);
}